// Round 6
// baseline (193.462 us; speedup 1.0000x reference)
//
#include <hip/hip_runtime.h>
#include <hip/hip_bf16.h>
#include <math.h>

// Problem: B=64, C=128, H=64, W=64, HW=4096
// out   : (B,C,H,W) f32 at d_out[0];  logdet: (B,) f32 at d_out[33554432]
//
// Algebra: pool[b,l] = sum_c wbar[c]*mask[c,l]*x[b,c,l] + bbar,
//   wbar[c] = mean_o w[o,c], bbar = mean(bias)  -> 128x128 mix never built.
// logdet[b] = 64 * sum_l log g[b,l] + B*(HW/2)*sum_c log s_sig[c]
//
// Round-6: two kernels. main = round-3's best-measured streaming body.
// fin folded in via last-block pattern: per-b padded counters (64 adds per
// 128B line over the kernel lifetime -- uncontended, unlike round-5's
// 2048-adds-per-line logdet atomics), agent-scope partial stores, and the
// 64 winning blocks do a wave-wide shuffle reduction. Release wait sits
// before the 32KB out-store burst so vmcnt(0) covers only a 4B store.

#define EPS 1e-5f
#define NC 128
#define NHW 4096
#define NB 64
#define LT 64            // pixels per block tile
#define NLT (NHW / LT)   // 64

typedef __attribute__((ext_vector_type(4))) float f4;

// ws layout:
//  floats [0..127]   wbar
//  floats [128..255] s_sig
//  float  [256]      bbar
//  float  [257]      logdet const term
//  floats [512 .. 512+NB*NLT)  per-tile log-g partials
//  ints   at float index 8192: counters, counter[b] = cnt[b*32] (128B apart)

__global__ __launch_bounds__(256) void prep_kernel(const float* __restrict__ w,
                                                   const float* __restrict__ bias,
                                                   const float* __restrict__ s,
                                                   float* __restrict__ ws) {
    __shared__ float wpart[256];
    __shared__ float lred[NC];
    __shared__ float bred[NC];

    const int tid = threadIdx.x;        // 256 threads
    // column c = tid&127, o-half = tid>>7: sum 64 rows (coalesced), 8 chains
    {
        const int c  = tid & 127;
        const int o0 = (tid >> 7) * 64;
        const float* __restrict__ wp = w + (size_t)o0 * NC + c;
        float a0 = 0.f, a1 = 0.f, a2 = 0.f, a3 = 0.f;
        float a4 = 0.f, a5 = 0.f, a6 = 0.f, a7 = 0.f;
#pragma unroll
        for (int o = 0; o < 64; o += 8) {
            a0 += wp[(o + 0) * NC];
            a1 += wp[(o + 1) * NC];
            a2 += wp[(o + 2) * NC];
            a3 += wp[(o + 3) * NC];
            a4 += wp[(o + 4) * NC];
            a5 += wp[(o + 5) * NC];
            a6 += wp[(o + 6) * NC];
            a7 += wp[(o + 7) * NC];
        }
        wpart[tid] = (((a0 + a1) + (a2 + a3)) + ((a4 + a5) + (a6 + a7)));
    }

    // zero the last-block counters (fresh every call; replays reuse ws)
    int* __restrict__ cnt = (int*)(ws + 8192);
    if (tid < NB) cnt[tid * 32] = 0;

    __syncthreads();

    if (tid < NC) {
        ws[tid] = (wpart[tid] + wpart[NC + tid]) * (1.f / NC);
        const float ssig = 1.f / (1.f + expf(-s[tid])) + EPS;
        ws[NC + tid] = ssig;
        lred[tid] = logf(ssig);
        bred[tid] = bias[tid];
    }
    __syncthreads();

    if (tid == 0) {
        double sb = 0.0, sl = 0.0;
        for (int i = 0; i < NC; ++i) { sb += (double)bred[i]; sl += (double)lred[i]; }
        ws[256] = (float)(sb / NC);
        // const term per batch: B*(HW/2)*sum_c log ssig
        ws[257] = (float)((double)NB * (double)(NHW / 2) * sl);
    }
}

__global__ __launch_bounds__(256) void main_kernel(const float* __restrict__ x,
                                                   float* __restrict__ ws,
                                                   const float* __restrict__ offp,
                                                   float* __restrict__ out,
                                                   float* __restrict__ logdet) {
    __shared__ float4 pp[4][16];   // 1 KiB: per-wave pool partials

    const int tid  = threadIdx.x;
    const int j    = tid & 15;     // pixel-quad index: pixels l0 + 4j .. 4j+3
    const int cg   = tid >> 4;     // channel group 0..15 (8 channels each)
    const int wave = tid >> 6;
    const int lane = tid & 63;

    const int lt = blockIdx.x;     // l-tile 0..63
    const int b  = blockIdx.y;     // batch
    const int l0 = lt * LT;        // multiple of 64 (even)

    const size_t base = (size_t)b * (NC * NHW) + (size_t)(cg * 8) * NHW + l0 + j * 4;
    const float* __restrict__ xp = x + base;

    // ---- load 8 float4 into registers ----
    float4 v[8];
#pragma unroll
    for (int k = 0; k < 8; ++k)
        v[k] = *reinterpret_cast<const float4*>(xp + (size_t)k * NHW);

    // ---- per-thread pool partial over its 8 channels ----
    float4 acc = make_float4(0.f, 0.f, 0.f, 0.f);
#pragma unroll
    for (int k = 0; k < 8; ++k) {
        const int c = cg * 8 + k;
        const float wb = ws[c];
        if (c & 1) { acc.x += wb * v[k].x; acc.z += wb * v[k].z; }
        else       { acc.y += wb * v[k].y; acc.w += wb * v[k].w; }
    }

    // ---- reduce over the 4 channel-groups within this wave ----
#pragma unroll
    for (int off = 16; off <= 32; off <<= 1) {
        acc.x += __shfl_xor(acc.x, off);
        acc.y += __shfl_xor(acc.y, off);
        acc.z += __shfl_xor(acc.z, off);
        acc.w += __shfl_xor(acc.w, off);
    }
    if (lane < 16) pp[wave][j] = acc;   // lane==j for lane<16
    __syncthreads();

    // ---- final pool + gate (redundant per thread; VALU is idle) ----
    const float4 p0 = pp[0][j], p1 = pp[1][j], p2 = pp[2][j], p3 = pp[3][j];
    const float cst = ws[256] + offp[0];
    float4 g;
    g.x = 1.f / (1.f + __expf(-(p0.x + p1.x + p2.x + p3.x + cst))) + EPS;
    g.y = 1.f / (1.f + __expf(-(p0.y + p1.y + p2.y + p3.y + cst))) + EPS;
    g.z = 1.f / (1.f + __expf(-(p0.z + p1.z + p2.z + p3.z + cst))) + EPS;
    g.w = 1.f / (1.f + __expf(-(p0.w + p1.w + p2.w + p3.w + cst))) + EPS;

    // ---- logdet: tile partial + last-block-per-batch finalize (wave 0) ----
    if (wave == 0) {
        float slg = (lane < 16)
                  ? (__logf(g.x) + __logf(g.y) + __logf(g.z) + __logf(g.w))
                  : 0.f;
#pragma unroll
        for (int off = 32; off > 0; off >>= 1) slg += __shfl_down(slg, off);

        float* __restrict__ partials = ws + 512;
        int*   __restrict__ cnt      = (int*)(ws + 8192);
        int last = 0;
        if (lane == 0) {
            // write-through agent-scope store; visible at coherence point
            __hip_atomic_store(&partials[b * NLT + lt], slg,
                               __ATOMIC_RELAXED, __HIP_MEMORY_SCOPE_AGENT);
            // release orders the partial store; acquire covers the reads below
            const int old = __hip_atomic_fetch_add(&cnt[b * 32], 1,
                               __ATOMIC_ACQ_REL, __HIP_MEMORY_SCOPE_AGENT);
            last = (old == NLT - 1);
        }
        last = __shfl(last, 0);
        if (last) {
            float p = __hip_atomic_load(&partials[b * NLT + lane],
                               __ATOMIC_RELAXED, __HIP_MEMORY_SCOPE_AGENT);
#pragma unroll
            for (int off = 32; off > 0; off >>= 1) p += __shfl_down(p, off);
            if (lane == 0) logdet[b] = 64.f * p + ws[257];   // (C//2)=64
        }
    }

    // ---- scale registers and store (non-temporal: write-once stream) ----
    const float* __restrict__ ssig = ws + NC;
    float* __restrict__ op = out + base;
#pragma unroll
    for (int k = 0; k < 8; ++k) {
        const int c = cg * 8 + k;
        const float sc = ssig[c];
        f4 o;
        if (c & 1) { o.x = v[k].x * sc;  o.y = v[k].y * g.y;
                     o.z = v[k].z * sc;  o.w = v[k].w * g.w; }
        else       { o.x = v[k].x * g.x; o.y = v[k].y * sc;
                     o.z = v[k].z * g.z; o.w = v[k].w * sc; }
        __builtin_nontemporal_store(o, reinterpret_cast<f4*>(op + (size_t)k * NHW));
    }
}

extern "C" void kernel_launch(void* const* d_in, const int* in_sizes, int n_in,
                              void* d_out, int out_size, void* d_ws, size_t ws_size,
                              hipStream_t stream) {
    const float* x    = (const float*)d_in[0];
    const float* w    = (const float*)d_in[1];
    const float* bias = (const float*)d_in[2];
    const float* s    = (const float*)d_in[3];
    const float* offp = (const float*)d_in[4];

    float* out    = (float*)d_out;
    float* logdet = out + (size_t)NB * NC * NHW;
    float* ws     = (float*)d_ws;

    prep_kernel<<<1, 256, 0, stream>>>(w, bias, s, ws);
    main_kernel<<<dim3(NLT, NB), 256, 0, stream>>>(x, ws, offp, out, logdet);
}

// Round 8
// 59.071 us; speedup vs baseline: 3.2751x; 3.2751x over previous
//
#include <hip/hip_runtime.h>
#include <hip/hip_bf16.h>
#include <math.h>

// Problem: B=64, C=128, H=64, W=64, HW=4096
// out   : (B,C,H,W) f32 at d_out[0];  logdet: (B,) f32 at d_out[33554432]
//
// Algebra: pool[b,l] = sum_c wbar[c]*mask[c,l]*x[b,c,l] + bbar,
//   wbar[c] = mean_o w[o,c], bbar = mean(bias)  -> 128x128 mix never built.
// logdet[b] = 64 * sum_l log g[b,l] + B*(HW/2)*sum_c log s_sig[c]
//
// Round-8 = round-7 resubmitted (container died; no measurement taken).
// 3-kernel round-3 structure (best measured, 52.1us) with LT=256 pixel
// tile and 1024-thread blocks: wave == one channel row -> every global
// load / nt store is a single fully-contiguous 1KiB transaction
// (16B/lane x 64), matching the copy-bench access pattern, instead of
// 4x256B per wave. Pool reduction = one LDS exchange, one barrier.

#define EPS 1e-5f
#define NC 128
#define NHW 4096
#define NB 64
#define LT 256             // pixels per block tile
#define NLT (NHW / LT)     // 16

typedef __attribute__((ext_vector_type(4))) float f4;

// ws layout (floats): [0..127] wbar, [128..255] s_sig, [256] bbar,
//                     [257] logdet const, [512..512+NB*NLT) partials

__global__ __launch_bounds__(256) void prep_kernel(const float* __restrict__ w,
                                                   const float* __restrict__ bias,
                                                   const float* __restrict__ s,
                                                   float* __restrict__ ws) {
    __shared__ float wpart[256];
    __shared__ float lred[NC];
    __shared__ float bred[NC];

    const int tid = threadIdx.x;        // 256 threads
    {
        const int c  = tid & 127;
        const int o0 = (tid >> 7) * 64;
        const float* __restrict__ wp = w + (size_t)o0 * NC + c;
        float a0 = 0.f, a1 = 0.f, a2 = 0.f, a3 = 0.f;
        float a4 = 0.f, a5 = 0.f, a6 = 0.f, a7 = 0.f;
#pragma unroll
        for (int o = 0; o < 64; o += 8) {
            a0 += wp[(o + 0) * NC];
            a1 += wp[(o + 1) * NC];
            a2 += wp[(o + 2) * NC];
            a3 += wp[(o + 3) * NC];
            a4 += wp[(o + 4) * NC];
            a5 += wp[(o + 5) * NC];
            a6 += wp[(o + 6) * NC];
            a7 += wp[(o + 7) * NC];
        }
        wpart[tid] = (((a0 + a1) + (a2 + a3)) + ((a4 + a5) + (a6 + a7)));
    }
    __syncthreads();

    if (tid < NC) {
        ws[tid] = (wpart[tid] + wpart[NC + tid]) * (1.f / NC);
        const float ssig = 1.f / (1.f + expf(-s[tid])) + EPS;
        ws[NC + tid] = ssig;
        lred[tid] = logf(ssig);
        bred[tid] = bias[tid];
    }
    __syncthreads();

    if (tid == 0) {
        double sb = 0.0, sl = 0.0;
        for (int i = 0; i < NC; ++i) { sb += (double)bred[i]; sl += (double)lred[i]; }
        ws[256] = (float)(sb / NC);
        ws[257] = (float)((double)NB * (double)(NHW / 2) * sl);
    }
}

__global__ __launch_bounds__(1024) void main_kernel(const float* __restrict__ x,
                                                    const float* __restrict__ ws,
                                                    const float* __restrict__ offp,
                                                    float* __restrict__ out,
                                                    float* __restrict__ partials) {
    __shared__ float4 pp[16][64];   // 16 KiB: per-wave (=per-cg) pool partials

    const int tid  = threadIdx.x;   // 1024
    const int j    = tid & 63;      // pixel-quad index: pixels l0 + 4j .. 4j+3
    const int cg   = tid >> 6;      // channel group 0..15 (8 channels) == wave id

    const int lt = blockIdx.x;      // l-tile 0..15
    const int b  = blockIdx.y;      // batch
    const int l0 = lt * LT;         // multiple of 256 (even)

    const size_t base = (size_t)b * (NC * NHW) + (size_t)(cg * 8) * NHW + l0 + j * 4;
    const float* __restrict__ xp = x + base;

    // ---- load 8 float4 into registers; each instr = 1KiB wave-contiguous ----
    float4 v[8];
#pragma unroll
    for (int k = 0; k < 8; ++k)
        v[k] = *reinterpret_cast<const float4*>(xp + (size_t)k * NHW);

    // ---- per-thread pool partial over its 8 channels ----
    float4 acc = make_float4(0.f, 0.f, 0.f, 0.f);
#pragma unroll
    for (int k = 0; k < 8; ++k) {
        const int c = cg * 8 + k;
        const float wb = ws[c];
        if (c & 1) { acc.x += wb * v[k].x; acc.z += wb * v[k].z; }
        else       { acc.y += wb * v[k].y; acc.w += wb * v[k].w; }
    }

    // ---- exchange across the 16 waves via LDS (single barrier) ----
    pp[cg][j] = acc;
    __syncthreads();

    // ---- final pool + gate (redundant per thread; VALU is idle) ----
    float4 p = pp[0][j];
#pragma unroll
    for (int wv = 1; wv < 16; ++wv) {
        const float4 q = pp[wv][j];
        p.x += q.x; p.y += q.y; p.z += q.z; p.w += q.w;
    }
    const float cst = ws[256] + offp[0];
    float4 g;
    g.x = 1.f / (1.f + __expf(-(p.x + cst))) + EPS;
    g.y = 1.f / (1.f + __expf(-(p.y + cst))) + EPS;
    g.z = 1.f / (1.f + __expf(-(p.z + cst))) + EPS;
    g.w = 1.f / (1.f + __expf(-(p.w + cst))) + EPS;

    // ---- logdet partial: wave 0 sums log(g) over this tile's 256 pixels ----
    if (cg == 0) {
        float slg = __logf(g.x) + __logf(g.y) + __logf(g.z) + __logf(g.w);
#pragma unroll
        for (int off = 32; off > 0; off >>= 1) slg += __shfl_down(slg, off);
        if (j == 0) partials[b * NLT + lt] = slg;
    }

    // ---- scale registers and store (non-temporal, 1KiB per instruction) ----
    const float* __restrict__ ssig = ws + NC;
    float* __restrict__ op = out + base;
#pragma unroll
    for (int k = 0; k < 8; ++k) {
        const int c = cg * 8 + k;
        const float sc = ssig[c];
        f4 o;
        if (c & 1) { o.x = v[k].x * sc;  o.y = v[k].y * g.y;
                     o.z = v[k].z * sc;  o.w = v[k].w * g.w; }
        else       { o.x = v[k].x * g.x; o.y = v[k].y * sc;
                     o.z = v[k].z * g.z; o.w = v[k].w * sc; }
        __builtin_nontemporal_store(o, reinterpret_cast<f4*>(op + (size_t)k * NHW));
    }
}

__global__ __launch_bounds__(64) void fin_kernel(const float* __restrict__ partials,
                                                 const float* __restrict__ ws,
                                                 float* __restrict__ logdet,
                                                 int nlt) {
    const int b = blockIdx.x;
    const int t = threadIdx.x;  // 64 threads
    float v = (t < nlt) ? partials[b * nlt + t] : 0.f;
#pragma unroll
    for (int off = 32; off > 0; off >>= 1) v += __shfl_down(v, off);
    if (t == 0) logdet[b] = 64.f * v + ws[257];  // (C//2) = 64
}

extern "C" void kernel_launch(void* const* d_in, const int* in_sizes, int n_in,
                              void* d_out, int out_size, void* d_ws, size_t ws_size,
                              hipStream_t stream) {
    const float* x    = (const float*)d_in[0];
    const float* w    = (const float*)d_in[1];
    const float* bias = (const float*)d_in[2];
    const float* s    = (const float*)d_in[3];
    const float* offp = (const float*)d_in[4];

    float* out    = (float*)d_out;
    float* logdet = out + (size_t)NB * NC * NHW;
    float* ws     = (float*)d_ws;
    float* partials = ws + 512;

    prep_kernel<<<1, 256, 0, stream>>>(w, bias, s, ws);
    main_kernel<<<dim3(NLT, NB), 1024, 0, stream>>>(x, ws, offp, out, partials);
    fin_kernel<<<NB, 64, 0, stream>>>(partials, ws, logdet, NLT);
}

// Round 9
// 51.046 us; speedup vs baseline: 3.7900x; 1.1572x over previous
//
#include <hip/hip_runtime.h>
#include <hip/hip_bf16.h>
#include <math.h>

// Problem: B=64, C=128, H=64, W=64, HW=4096
// out   : (B,C,H,W) f32 at d_out[0];  logdet: (B,) f32 at d_out[33554432]
//
// Algebra: pool[b,l] = sum_c wbar[c]*mask[c,l]*x[b,c,l] + bbar,
//   wbar[c] = mean_o w[o,c], bbar = mean(bias)  -> 128x128 mix never built.
// logdet[b] = 64 * sum_l log g[b,l] + B*(HW/2)*sum_c log s_sig[c]
//
// Round-9: main+fin are byte-for-byte round-3 (best measured, 52.1us).
// prep rewritten latency-optimal: 16 INDEPENDENT float4 loads per thread
// (coalesced along w rows, one HBM round-trip) + LDS transpose-reduce,
// and shuffle reductions instead of the serial 128-iter double loops.

#define EPS 1e-5f
#define NC 128
#define NHW 4096
#define NB 64
#define LT 64            // pixels per block tile
#define NLT (NHW / LT)   // 64

typedef __attribute__((ext_vector_type(4))) float f4;

// ws layout (floats): [0..127] wbar, [128..255] s_sig, [256] bbar,
//                     [257] logdet const, [512..512+NB*NLT) partials

__global__ __launch_bounds__(256) void prep_kernel(const float* __restrict__ w,
                                                   const float* __restrict__ bias,
                                                   const float* __restrict__ s,
                                                   float* __restrict__ ws) {
    __shared__ float wred[8][NC];   // [o-range][c] partial column sums
    __shared__ float lw[4], bw[4];

    const int tid = threadIdx.x;    // 256 threads
    const int q   = tid & 31;       // c-quad (4 channels)
    const int r   = tid >> 5;       // o-range 0..7 (16 rows each)

    // ---- 16 independent coalesced float4 loads; single memory round-trip ----
    {
        const float* __restrict__ wp = w + (size_t)(r * 16) * NC + q * 4;
        float4 a = make_float4(0.f, 0.f, 0.f, 0.f);
#pragma unroll
        for (int o = 0; o < 16; ++o) {
            const float4 v = *reinterpret_cast<const float4*>(wp + (size_t)o * NC);
            a.x += v.x; a.y += v.y; a.z += v.z; a.w += v.w;
        }
        *reinterpret_cast<float4*>(&wred[r][q * 4]) = a;
    }
    __syncthreads();

    // ---- finalize per-channel params; shuffle-reduce bias & log s_sig ----
    float lv = 0.f, bv = 0.f;
    if (tid < NC) {
        float sum = 0.f;
#pragma unroll
        for (int rr = 0; rr < 8; ++rr) sum += wred[rr][tid];
        ws[tid] = sum * (1.f / NC);                    // wbar
        const float ssig = 1.f / (1.f + __expf(-s[tid])) + EPS;
        ws[NC + tid] = ssig;                           // s_sig
        lv = __logf(ssig);
        bv = bias[tid];
    }
#pragma unroll
    for (int off = 32; off > 0; off >>= 1) {
        lv += __shfl_down(lv, off);
        bv += __shfl_down(bv, off);
    }
    const int wave = tid >> 6;
    if ((tid & 63) == 0) { lw[wave] = lv; bw[wave] = bv; }
    __syncthreads();
    if (tid == 0) {
        const float sl = lw[0] + lw[1] + lw[2] + lw[3];
        const float sb = bw[0] + bw[1] + bw[2] + bw[3];
        ws[256] = sb * (1.f / NC);                     // bbar
        ws[257] = (float)NB * (float)(NHW / 2) * sl;   // logdet const
    }
}

__global__ __launch_bounds__(256) void main_kernel(const float* __restrict__ x,
                                                   const float* __restrict__ ws,
                                                   const float* __restrict__ offp,
                                                   float* __restrict__ out,
                                                   float* __restrict__ partials) {
    __shared__ float4 pp[4][16];   // 1 KiB: per-wave pool partials

    const int tid  = threadIdx.x;
    const int j    = tid & 15;     // pixel-quad index: pixels l0 + 4j .. 4j+3
    const int cg   = tid >> 4;     // channel group 0..15 (8 channels each)
    const int wave = tid >> 6;
    const int lane = tid & 63;

    const int lt = blockIdx.x;     // l-tile 0..63
    const int b  = blockIdx.y;     // batch
    const int l0 = lt * LT;        // multiple of 64 (even)

    const size_t base = (size_t)b * (NC * NHW) + (size_t)(cg * 8) * NHW + l0 + j * 4;
    const float* __restrict__ xp = x + base;

    // ---- load 8 float4 into registers ----
    float4 v[8];
#pragma unroll
    for (int k = 0; k < 8; ++k)
        v[k] = *reinterpret_cast<const float4*>(xp + (size_t)k * NHW);

    // ---- per-thread pool partial over its 8 channels ----
    float4 acc = make_float4(0.f, 0.f, 0.f, 0.f);
#pragma unroll
    for (int k = 0; k < 8; ++k) {
        const int c = cg * 8 + k;
        const float wb = ws[c];
        if (c & 1) { acc.x += wb * v[k].x; acc.z += wb * v[k].z; }
        else       { acc.y += wb * v[k].y; acc.w += wb * v[k].w; }
    }

    // ---- reduce over the 4 channel-groups within this wave ----
#pragma unroll
    for (int off = 16; off <= 32; off <<= 1) {
        acc.x += __shfl_xor(acc.x, off);
        acc.y += __shfl_xor(acc.y, off);
        acc.z += __shfl_xor(acc.z, off);
        acc.w += __shfl_xor(acc.w, off);
    }
    if (lane < 16) pp[wave][j] = acc;   // lane==j for lane<16
    __syncthreads();

    // ---- final pool + gate (redundant per thread; VALU is idle) ----
    const float4 p0 = pp[0][j], p1 = pp[1][j], p2 = pp[2][j], p3 = pp[3][j];
    const float cst = ws[256] + offp[0];
    float4 g;
    g.x = 1.f / (1.f + __expf(-(p0.x + p1.x + p2.x + p3.x + cst))) + EPS;
    g.y = 1.f / (1.f + __expf(-(p0.y + p1.y + p2.y + p3.y + cst))) + EPS;
    g.z = 1.f / (1.f + __expf(-(p0.z + p1.z + p2.z + p3.z + cst))) + EPS;
    g.w = 1.f / (1.f + __expf(-(p0.w + p1.w + p2.w + p3.w + cst))) + EPS;

    // ---- logdet: per-block sum of log(g) (wave 0) ----
    if (wave == 0) {
        float slg = (lane < 16)
                  ? (__logf(g.x) + __logf(g.y) + __logf(g.z) + __logf(g.w))
                  : 0.f;
#pragma unroll
        for (int off = 32; off > 0; off >>= 1) slg += __shfl_down(slg, off);
        if (lane == 0) partials[b * gridDim.x + lt] = slg;
    }

    // ---- scale registers and store (non-temporal: write-once stream) ----
    const float* __restrict__ ssig = ws + NC;
    float* __restrict__ op = out + base;
#pragma unroll
    for (int k = 0; k < 8; ++k) {
        const int c = cg * 8 + k;
        const float sc = ssig[c];
        f4 o;
        if (c & 1) { o.x = v[k].x * sc;  o.y = v[k].y * g.y;
                     o.z = v[k].z * sc;  o.w = v[k].w * g.w; }
        else       { o.x = v[k].x * g.x; o.y = v[k].y * sc;
                     o.z = v[k].z * g.z; o.w = v[k].w * sc; }
        __builtin_nontemporal_store(o, reinterpret_cast<f4*>(op + (size_t)k * NHW));
    }
}

__global__ __launch_bounds__(64) void fin_kernel(const float* __restrict__ partials,
                                                 const float* __restrict__ ws,
                                                 float* __restrict__ logdet,
                                                 int nlt) {
    const int b = blockIdx.x;
    const int t = threadIdx.x;  // 64 threads
    float v = (t < nlt) ? partials[b * nlt + t] : 0.f;
#pragma unroll
    for (int off = 32; off > 0; off >>= 1) v += __shfl_down(v, off);
    if (t == 0) logdet[b] = 64.f * v + ws[257];  // (C//2) = 64
}

extern "C" void kernel_launch(void* const* d_in, const int* in_sizes, int n_in,
                              void* d_out, int out_size, void* d_ws, size_t ws_size,
                              hipStream_t stream) {
    const float* x    = (const float*)d_in[0];
    const float* w    = (const float*)d_in[1];
    const float* bias = (const float*)d_in[2];
    const float* s    = (const float*)d_in[3];
    const float* offp = (const float*)d_in[4];

    float* out    = (float*)d_out;
    float* logdet = out + (size_t)NB * NC * NHW;
    float* ws     = (float*)d_ws;
    float* partials = ws + 512;

    prep_kernel<<<1, 256, 0, stream>>>(w, bias, s, ws);
    main_kernel<<<dim3(NLT, NB), 256, 0, stream>>>(x, ws, offp, out, partials);
    fin_kernel<<<NB, 64, 0, stream>>>(partials, ws, logdet, NLT);
}